// Round 13
// baseline (149.586 us; speedup 1.0000x reference)
//
#include <hip/hip_runtime.h>
#include <hip/hip_bf16.h>

#define NPIX 16384   // H*W
#define NC   48      // DIM

typedef __attribute__((ext_vector_type(16))) float f32x16;
typedef __attribute__((ext_vector_type(8))) short short8v;
typedef __attribute__((ext_vector_type(8))) unsigned short ushort8v;
typedef __attribute__((ext_vector_type(2))) unsigned int uint2v;

static __device__ __forceinline__ unsigned short f2bf(float x) {
  union { float f; unsigned u; } v; v.f = x;
  unsigned r = v.u + 0x7fffu + ((v.u >> 16) & 1u);
  return (unsigned short)(r >> 16);
}
static __device__ __forceinline__ float bf2f(unsigned short b) {
  union { unsigned u; float f; } v; v.u = ((unsigned)b) << 16;
  return v.f;
}

// ---------------- kernel 1: pointwise conv  out[o][p] = sum_c w[o][c]*in[c][p]
__global__ __launch_bounds__(256) void k_pointwise(const float* __restrict__ in,
                                                   const float* __restrict__ w,
                                                   float* __restrict__ out) {
  int p = blockIdx.x * 256 + threadIdx.x;
  int og = blockIdx.y * 16;
  __shared__ float wl[16][NC];
  for (int i = threadIdx.x; i < 16 * NC; i += 256)
    wl[i / NC][i % NC] = w[(og + i / NC) * NC + i % NC];
  __syncthreads();
  float acc[16];
#pragma unroll
  for (int j = 0; j < 16; ++j) acc[j] = 0.f;
  for (int c = 0; c < NC; ++c) {
    float xv = in[c * NPIX + p];
#pragma unroll
    for (int j = 0; j < 16; ++j) acc[j] += xv * wl[j][c];
  }
#pragma unroll
  for (int j = 0; j < 16; ++j) out[(og + j) * NPIX + p] = acc[j];
}

// ---------------- kernel 2: depthwise 3x3, SAME pad; writes bf16 channel-major
__global__ __launch_bounds__(256) void k_dwconv(const float* __restrict__ in,
                                                const float* __restrict__ w,
                                                unsigned short* __restrict__ out) {
  int p = blockIdx.x * 256 + threadIdx.x;
  int o = blockIdx.y;
  int y = p >> 7, xx = p & 127;
  const float* base = in + o * NPIX;
  const float* wt = w + o * 9;
  float acc = 0.f;
#pragma unroll
  for (int dy = -1; dy <= 1; ++dy)
#pragma unroll
    for (int dx = -1; dx <= 1; ++dx) {
      int yy = y + dy, xc = xx + dx;
      if (yy >= 0 && yy < 128 && xc >= 0 && xc < 128)
        acc += wt[(dy + 1) * 3 + (dx + 1)] * base[yy * 128 + xc];
    }
  out[o * NPIX + p] = f2bf(acc);
}

// ---------------- kernel 3: per-token l2norm of q,k (bf16 in) -> bf16 out.
// q additionally scaled by t*log2(e) so attn softmax uses native exp2.
__global__ __launch_bounds__(64) void k_norm(const unsigned short* __restrict__ dwqb,
                                             const float* __restrict__ temp,
                                             unsigned short* __restrict__ qn,
                                             unsigned short* __restrict__ kn) {
  int p = blockIdx.x * 64 + threadIdx.x;
  float t = temp[0] * 1.44269504088896f;  // fold log2(e) into temperature
  float qv[48], kv[48];
  float sq = 0.f, sk = 0.f;
#pragma unroll
  for (int c = 0; c < 48; ++c) {
    qv[c] = bf2f(dwqb[c * NPIX + p]);
    kv[c] = bf2f(dwqb[(48 + c) * NPIX + p]);
    sq += qv[c] * qv[c];
    sk += kv[c] * kv[c];
  }
  float rq = t / fmaxf(sqrtf(sq), 1e-12f);
  float rk = 1.f / fmaxf(sqrtf(sk), 1e-12f);
  unsigned short qb[48], kb[48];
#pragma unroll
  for (int c = 0; c < 48; ++c) {
    qb[c] = f2bf(qv[c] * rq);
    kb[c] = f2bf(kv[c] * rk);
  }
#pragma unroll
  for (int j = 0; j < 6; ++j) {
    *(ushort8v*)(qn + p * 48 + j * 8) = *(ushort8v*)&qb[j * 8];
    *(ushort8v*)(kn + p * 48 + j * 8) = *(ushort8v*)&kb[j * 8];
  }
}

// ---------------- kernel 4: MFMA attention NS=8, 2 Q-SETS PER WAVE.
// Each wave owns 64 q-rows (two 32-row B-operands): every K/V LDS read feeds
// TWO MFMAs (reads/MFMA 1.0 -> 0.5; LDS pipe was the top consumer at ~48%).
// Block = 4 waves = 256 q-rows x 2048-key split; grid 64x8 = 512 (2/CU).
// Staging/swizzles/sync identical to the r11-verified kernel.
// NO min-waves clause — (,N) provably corrupts this kernel (r8 vs r9).
__global__ __launch_bounds__(256) void k_attn8(const unsigned short* __restrict__ qn,
                                               const unsigned short* __restrict__ kn,
                                               const unsigned short* __restrict__ vb,
                                               float* __restrict__ num) {
  __shared__ __align__(16) char smem[28672];  // K 12288 B + Vt 16384 B (1 buf)
  const int tid = threadIdx.x;
  const int lane = tid & 63, wid = tid >> 6;
  const int l31 = lane & 31, lh = lane >> 5;
  const int bidx = blockIdx.x;
  const int ks = bidx & 7;
  const int qb = bidx >> 3;
  const int qbase0 = qb * 256 + wid * 32;        // q-set 0
  const int qbase1 = qbase0 + 128;               // q-set 1

  short8v qf0[3], qf1[3];
#pragma unroll
  for (int s = 0; s < 3; ++s) {
    qf0[s] = *(const short8v*)(qn + (qbase0 + l31) * 48 + s * 16 + lh * 8);
    qf1[s] = *(const short8v*)(qn + (qbase1 + l31) * 48 + s * 16 + lh * 8);
  }

  f32x16 acc[2][2];  // [q-set][c-block]
#pragma unroll
  for (int a = 0; a < 2; ++a)
#pragma unroll
    for (int b = 0; b < 2; ++b)
#pragma unroll
      for (int r = 0; r < 16; ++r) acc[a][b][r] = 0.f;

  // t-invariant staging maps
  int kgoff[3], kloff[3], vgoff[3], vloff[3];
#pragma unroll
  for (int i = 0; i < 3; ++i) {
    int chunk = tid + 256 * i;
    int key = chunk / 6, part = chunk - key * 6;
    kgoff[i] = key * 48 + part * 8;
    kloff[i] = (key * 96 + part * 16) ^ ((key & 7) << 4);
    int c2 = chunk >> 4, kp = chunk & 15;
    vgoff[i] = c2 * NPIX + kp * 8;
    vloff[i] = 12288 + ((c2 * 256 + kp * 16) ^ ((c2 & 15) << 4));
  }

  // Vt pad rows 48..63: row 48 = ones (den), rest zero. Written once.
  {
    int c = 48 + (tid >> 4), kp = tid & 15;
    unsigned short val = (c == 48) ? (unsigned short)0x3F80 : (unsigned short)0;
    ushort8v vv = {val, val, val, val, val, val, val, val};
    *(ushort8v*)(smem + 12288 + ((c * 256 + kp * 16) ^ ((c & 15) << 4))) = vv;
  }
  // prologue: stage tile 0
  {
    const int m0 = ks * 2048;
#pragma unroll
    for (int i = 0; i < 3; ++i) {
      *(short8v*)(smem + kloff[i]) = *(const short8v*)(kn + m0 * 48 + kgoff[i]);
      *(short8v*)(smem + vloff[i]) = *(const short8v*)(vb + m0 + vgoff[i]);
    }
  }
  __syncthreads();

  for (int t = 0; t < 16; ++t) {
    // ---- T14 issue-early: global loads for tile t+1 into registers ----
    short8v pfk[3], pfv[3];
    const bool hasNext = (t + 1 < 16);
    if (hasNext) {
      const int m0n = ks * 2048 + (t + 1) * 128;
#pragma unroll
      for (int i = 0; i < 3; ++i) {
        pfk[i] = *(const short8v*)(kn + m0n * 48 + kgoff[i]);
        pfv[i] = *(const short8v*)(vb + m0n + vgoff[i]);
      }
    }
    // ---- compute tile t: each kf/vf read feeds both q-sets ----
#pragma unroll
    for (int kb = 0; kb < 128; kb += 32) {
      f32x16 s0, s1;
#pragma unroll
      for (int r = 0; r < 16; ++r) { s0[r] = 0.f; s1[r] = 0.f; }
      int key = kb + l31;
#pragma unroll
      for (int s = 0; s < 3; ++s) {
        short8v kf = *(const short8v*)(smem +
            ((key * 96 + s * 32 + lh * 16) ^ ((key & 7) << 4)));
        s0 = __builtin_amdgcn_mfma_f32_32x32x16_bf16(kf, qf0[s], s0, 0, 0, 0);
        s1 = __builtin_amdgcn_mfma_f32_32x32x16_bf16(kf, qf1[s], s1, 0, 0, 0);
      }
      float p0[16], p1[16];
#pragma unroll
      for (int r = 0; r < 16; ++r) p0[r] = __builtin_amdgcn_exp2f(s0[r]);
#pragma unroll
      for (int r = 0; r < 16; ++r) p1[r] = __builtin_amdgcn_exp2f(s1[r]);
#pragma unroll
      for (int h = 0; h < 2; ++h) {
        unsigned a0, a1, b0, b1, c0, c1u, d0, d1;
        asm("v_cvt_pk_bf16_f32 %0, %1, %2" : "=v"(a0) : "v"(p0[8 * h + 0]), "v"(p0[8 * h + 1]));
        asm("v_cvt_pk_bf16_f32 %0, %1, %2" : "=v"(a1) : "v"(p0[8 * h + 2]), "v"(p0[8 * h + 3]));
        asm("v_cvt_pk_bf16_f32 %0, %1, %2" : "=v"(b0) : "v"(p0[8 * h + 4]), "v"(p0[8 * h + 5]));
        asm("v_cvt_pk_bf16_f32 %0, %1, %2" : "=v"(b1) : "v"(p0[8 * h + 6]), "v"(p0[8 * h + 7]));
        asm("v_cvt_pk_bf16_f32 %0, %1, %2" : "=v"(c0) : "v"(p1[8 * h + 0]), "v"(p1[8 * h + 1]));
        asm("v_cvt_pk_bf16_f32 %0, %1, %2" : "=v"(c1u) : "v"(p1[8 * h + 2]), "v"(p1[8 * h + 3]));
        asm("v_cvt_pk_bf16_f32 %0, %1, %2" : "=v"(d0) : "v"(p1[8 * h + 4]), "v"(p1[8 * h + 5]));
        asm("v_cvt_pk_bf16_f32 %0, %1, %2" : "=v"(d1) : "v"(p1[8 * h + 6]), "v"(p1[8 * h + 7]));
        uint2v w0 = __builtin_amdgcn_permlane32_swap(a0, b0, false, false);
        uint2v w1 = __builtin_amdgcn_permlane32_swap(a1, b1, false, false);
        uint2v w2 = __builtin_amdgcn_permlane32_swap(c0, d0, false, false);
        uint2v w3 = __builtin_amdgcn_permlane32_swap(c1u, d1, false, false);
        union { unsigned u[4]; short8v v; } pa0, pa1;
        pa0.u[0] = w0[0]; pa0.u[1] = w1[0]; pa0.u[2] = w0[1]; pa0.u[3] = w1[1];
        pa1.u[0] = w2[0]; pa1.u[1] = w3[0]; pa1.u[2] = w2[1]; pa1.u[3] = w3[1];
        int kbase = kb + 16 * h + 8 * lh;
        short8v vf0 = *(const short8v*)(smem + 12288 +
            ((l31 * 256 + kbase * 2) ^ ((l31 & 15) << 4)));
        acc[0][0] = __builtin_amdgcn_mfma_f32_32x32x16_bf16(pa0.v, vf0, acc[0][0], 0, 0, 0);
        acc[1][0] = __builtin_amdgcn_mfma_f32_32x32x16_bf16(pa1.v, vf0, acc[1][0], 0, 0, 0);
        int cc = 32 + l31;
        short8v vf1 = *(const short8v*)(smem + 12288 +
            ((cc * 256 + kbase * 2) ^ ((cc & 15) << 4)));
        acc[0][1] = __builtin_amdgcn_mfma_f32_32x32x16_bf16(pa0.v, vf1, acc[0][1], 0, 0, 0);
        acc[1][1] = __builtin_amdgcn_mfma_f32_32x32x16_bf16(pa1.v, vf1, acc[1][1], 0, 0, 0);
      }
    }
    __syncthreads();  // all waves done READING tile t
    // ---- T14 write-late: park prefetched tile t+1 ----
    if (hasNext) {
#pragma unroll
      for (int i = 0; i < 3; ++i) {
        *(short8v*)(smem + kloff[i]) = pfk[i];
        *(short8v*)(smem + vloff[i]) = pfv[i];
      }
    }
    __syncthreads();  // writes visible before next compute
  }

  // ---- epilogue: per q-set, transpose O through LDS (per-wave region), store
  float* ot = (float*)smem + wid * (32 * 52);
#pragma unroll
  for (int set = 0; set < 2; ++set) {
    const int qbase = (set == 0) ? qbase0 : qbase1;
    __syncthreads();
#pragma unroll
    for (int r = 0; r < 16; ++r) {
      int q = (r & 3) + 8 * (r >> 2) + 4 * lh;
      ot[q * 52 + l31] = acc[set][0][r];
      if (l31 < 17) ot[q * 52 + 32 + l31] = acc[set][1][r];
    }
    __syncthreads();
    for (int idx = lane; idx < 49 * 32; idx += 64) {
      int q = idx & 31, c = idx >> 5;
      num[((ks * 49 + c) << 14) + qbase + q] = ot[q * 52 + c];
    }
  }
}

// ---------------- kernel 5: combine key-splits and divide -> tokT [c][p]
__global__ __launch_bounds__(256) void k_combine(const float* __restrict__ num,
                                                 float* __restrict__ tokT) {
  int p = blockIdx.x * 256 + threadIdx.x;
  int c = blockIdx.y;
  float d = 0.f, s = 0.f;
#pragma unroll
  for (int ks = 0; ks < 8; ++ks) {
    d += num[(ks * 49 + 48) * NPIX + p];
    s += num[(ks * 49 + c) * NPIX + p];
  }
  tokT[c * NPIX + p] = s / d;
}

extern "C" void kernel_launch(void* const* d_in, const int* in_sizes, int n_in,
                              void* d_out, int out_size, void* d_ws, size_t ws_size,
                              hipStream_t stream) {
  const float* x      = (const float*)d_in[0];
  const float* qkv_w  = (const float*)d_in[1];
  const float* dw_w   = (const float*)d_in[2];
  const float* proj_w = (const float*)d_in[3];
  const float* temp   = (const float*)d_in[4];

  // workspace layout (bytes), peak 33.55 MB (proven available r9-r11):
  //   qn   bf16 [16384][48] @ 0         (dead after attn)
  //   kn   bf16 [16384][48] @ 1572864   (dead after attn)
  //   dwqb bf16 [144][16384] @ 3145728  (ch 96..143 = vb, live in attn)
  //   qkv  f32  [144][16384] @ 7864320  (dead after dwconv)
  //   num  f32  [8][49][16384] @ 7864320 (overlays dead qkv)
  //   tokT f32  [48][16384] @ 0         (overlays dead qn/kn)
  char* wsb = (char*)d_ws;
  unsigned short* qn   = (unsigned short*)wsb;
  unsigned short* kn   = (unsigned short*)(wsb + 1572864);
  unsigned short* dwqb = (unsigned short*)(wsb + 3145728);
  unsigned short* vb   = dwqb + 96 * NPIX;
  float* qkv  = (float*)(wsb + 7864320);
  float* num  = (float*)(wsb + 7864320);
  float* tokT = (float*)wsb;

  k_pointwise<<<dim3(64, 9), 256, 0, stream>>>(x, qkv_w, qkv);
  k_dwconv<<<dim3(64, 144), 256, 0, stream>>>(qkv, dw_w, dwqb);
  k_norm<<<dim3(256), 64, 0, stream>>>(dwqb, temp, qn, kn);
  k_attn8<<<dim3(512), 256, 0, stream>>>(qn, kn, vb, num);
  k_combine<<<dim3(64, 48), 256, 0, stream>>>(num, tokT);
  k_pointwise<<<dim3(64, 3), 256, 0, stream>>>(tokT, proj_w, (float*)d_out);
}

// Round 14
// 134.445 us; speedup vs baseline: 1.1126x; 1.1126x over previous
//
#include <hip/hip_runtime.h>
#include <hip/hip_bf16.h>

#define NPIX 16384   // H*W
#define NC   48      // DIM

typedef __attribute__((ext_vector_type(16))) float f32x16;
typedef __attribute__((ext_vector_type(8))) short short8v;
typedef __attribute__((ext_vector_type(8))) unsigned short ushort8v;
typedef __attribute__((ext_vector_type(2))) unsigned int uint2v;

static __device__ __forceinline__ unsigned short f2bf(float x) {
  union { float f; unsigned u; } v; v.f = x;
  unsigned r = v.u + 0x7fffu + ((v.u >> 16) & 1u);
  return (unsigned short)(r >> 16);
}
static __device__ __forceinline__ float bf2f(unsigned short b) {
  union { unsigned u; float f; } v; v.u = ((unsigned)b) << 16;
  return v.f;
}

// ---------------- kernel 1: pointwise qkv conv -> bf16 channel-major
__global__ __launch_bounds__(256) void k_qkv(const float* __restrict__ in,
                                             const float* __restrict__ w,
                                             unsigned short* __restrict__ out) {
  int p = blockIdx.x * 256 + threadIdx.x;
  int og = blockIdx.y * 16;
  __shared__ float wl[16][NC];
  for (int i = threadIdx.x; i < 16 * NC; i += 256)
    wl[i / NC][i % NC] = w[(og + i / NC) * NC + i % NC];
  __syncthreads();
  float acc[16];
#pragma unroll
  for (int j = 0; j < 16; ++j) acc[j] = 0.f;
  for (int c = 0; c < NC; ++c) {
    float xv = in[c * NPIX + p];
#pragma unroll
    for (int j = 0; j < 16; ++j) acc[j] += xv * wl[j][c];
  }
#pragma unroll
  for (int j = 0; j < 16; ++j) out[(og + j) * NPIX + p] = f2bf(acc[j]);
}

// ---------------- kernel 2: depthwise 3x3 (bf16 in), SAME pad -> bf16 out
__global__ __launch_bounds__(256) void k_dwconv(const unsigned short* __restrict__ in,
                                                const float* __restrict__ w,
                                                unsigned short* __restrict__ out) {
  int p = blockIdx.x * 256 + threadIdx.x;
  int o = blockIdx.y;
  int y = p >> 7, xx = p & 127;
  const unsigned short* base = in + o * NPIX;
  const float* wt = w + o * 9;
  float acc = 0.f;
#pragma unroll
  for (int dy = -1; dy <= 1; ++dy)
#pragma unroll
    for (int dx = -1; dx <= 1; ++dx) {
      int yy = y + dy, xc = xx + dx;
      if (yy >= 0 && yy < 128 && xc >= 0 && xc < 128)
        acc += wt[(dy + 1) * 3 + (dx + 1)] * bf2f(base[yy * 128 + xc]);
    }
  out[o * NPIX + p] = f2bf(acc);
}

// ---------------- kernel 3: per-token l2norm of q,k (bf16 in) -> bf16 out.
// q additionally scaled by t*log2(e) so attn softmax uses native exp2.
__global__ __launch_bounds__(64) void k_norm(const unsigned short* __restrict__ dwqb,
                                             const float* __restrict__ temp,
                                             unsigned short* __restrict__ qn,
                                             unsigned short* __restrict__ kn) {
  int p = blockIdx.x * 64 + threadIdx.x;
  float t = temp[0] * 1.44269504088896f;  // fold log2(e) into temperature
  float qv[48], kv[48];
  float sq = 0.f, sk = 0.f;
#pragma unroll
  for (int c = 0; c < 48; ++c) {
    qv[c] = bf2f(dwqb[c * NPIX + p]);
    kv[c] = bf2f(dwqb[(48 + c) * NPIX + p]);
    sq += qv[c] * qv[c];
    sk += kv[c] * kv[c];
  }
  float rq = t / fmaxf(sqrtf(sq), 1e-12f);
  float rk = 1.f / fmaxf(sqrtf(sk), 1e-12f);
  unsigned short qb[48], kb[48];
#pragma unroll
  for (int c = 0; c < 48; ++c) {
    qb[c] = f2bf(qv[c] * rq);
    kb[c] = f2bf(kv[c] * rk);
  }
#pragma unroll
  for (int j = 0; j < 6; ++j) {
    *(ushort8v*)(qn + p * 48 + j * 8) = *(ushort8v*)&qb[j * 8];
    *(ushort8v*)(kn + p * 48 + j * 8) = *(ushort8v*)&kb[j * 8];
  }
}

// ---------------- kernel 4: MFMA attention NS=8 (EXACT round-11 verified
// kernel — best measured: 90.4 us). Single-buffer + T14 prefetch; Vt swizzle
// ((c&15)<<4); grid 1024: ks=bidx&7 (one split per XCD), qb=bidx>>3.
// NO min-waves clause — (,N) provably corrupts this kernel (r8 vs r9).
__global__ __launch_bounds__(256) void k_attn8(const unsigned short* __restrict__ qn,
                                               const unsigned short* __restrict__ kn,
                                               const unsigned short* __restrict__ vb,
                                               float* __restrict__ num) {
  __shared__ __align__(16) char smem[28672];  // K 12288 B + Vt 16384 B (1 buf)
  const int tid = threadIdx.x;
  const int lane = tid & 63, wid = tid >> 6;
  const int l31 = lane & 31, lh = lane >> 5;
  const int bidx = blockIdx.x;
  const int ks = bidx & 7;
  const int qb = bidx >> 3;
  const int qbase = qb * 128 + wid * 32;

  short8v qf[3];
#pragma unroll
  for (int s = 0; s < 3; ++s)
    qf[s] = *(const short8v*)(qn + (qbase + l31) * 48 + s * 16 + lh * 8);

  f32x16 acc[2];  // [c-block]
#pragma unroll
  for (int b = 0; b < 2; ++b)
#pragma unroll
    for (int r = 0; r < 16; ++r) acc[b][r] = 0.f;

  // t-invariant staging maps
  int kgoff[3], kloff[3], vgoff[3], vloff[3];
#pragma unroll
  for (int i = 0; i < 3; ++i) {
    int chunk = tid + 256 * i;
    int key = chunk / 6, part = chunk - key * 6;
    kgoff[i] = key * 48 + part * 8;
    kloff[i] = (key * 96 + part * 16) ^ ((key & 7) << 4);
    int c2 = chunk >> 4, kp = chunk & 15;
    vgoff[i] = c2 * NPIX + kp * 8;
    vloff[i] = 12288 + ((c2 * 256 + kp * 16) ^ ((c2 & 15) << 4));
  }

  // Vt pad rows 48..63: row 48 = ones (den), rest zero. Written once.
  {
    int c = 48 + (tid >> 4), kp = tid & 15;
    unsigned short val = (c == 48) ? (unsigned short)0x3F80 : (unsigned short)0;
    ushort8v vv = {val, val, val, val, val, val, val, val};
    *(ushort8v*)(smem + 12288 + ((c * 256 + kp * 16) ^ ((c & 15) << 4))) = vv;
  }
  // prologue: stage tile 0
  {
    const int m0 = ks * 2048;
#pragma unroll
    for (int i = 0; i < 3; ++i) {
      *(short8v*)(smem + kloff[i]) = *(const short8v*)(kn + m0 * 48 + kgoff[i]);
      *(short8v*)(smem + vloff[i]) = *(const short8v*)(vb + m0 + vgoff[i]);
    }
  }
  __syncthreads();

  for (int t = 0; t < 16; ++t) {
    // ---- T14 issue-early: global loads for tile t+1 into registers ----
    short8v pfk[3], pfv[3];
    const bool hasNext = (t + 1 < 16);
    if (hasNext) {
      const int m0n = ks * 2048 + (t + 1) * 128;
#pragma unroll
      for (int i = 0; i < 3; ++i) {
        pfk[i] = *(const short8v*)(kn + m0n * 48 + kgoff[i]);
        pfv[i] = *(const short8v*)(vb + m0n + vgoff[i]);
      }
    }
    // ---- compute tile t ----
#pragma unroll
    for (int kb = 0; kb < 128; kb += 32) {
      f32x16 sacc;
#pragma unroll
      for (int r = 0; r < 16; ++r) sacc[r] = 0.f;
      int key = kb + l31;
#pragma unroll
      for (int s = 0; s < 3; ++s) {
        short8v kf = *(const short8v*)(smem +
            ((key * 96 + s * 32 + lh * 16) ^ ((key & 7) << 4)));
        sacc = __builtin_amdgcn_mfma_f32_32x32x16_bf16(kf, qf[s], sacc, 0, 0, 0);
      }
      float p[16];
#pragma unroll
      for (int r = 0; r < 16; ++r) p[r] = __builtin_amdgcn_exp2f(sacc[r]);
#pragma unroll
      for (int h = 0; h < 2; ++h) {
        unsigned a0, a1, b0, b1;
        asm("v_cvt_pk_bf16_f32 %0, %1, %2" : "=v"(a0) : "v"(p[8 * h + 0]), "v"(p[8 * h + 1]));
        asm("v_cvt_pk_bf16_f32 %0, %1, %2" : "=v"(a1) : "v"(p[8 * h + 2]), "v"(p[8 * h + 3]));
        asm("v_cvt_pk_bf16_f32 %0, %1, %2" : "=v"(b0) : "v"(p[8 * h + 4]), "v"(p[8 * h + 5]));
        asm("v_cvt_pk_bf16_f32 %0, %1, %2" : "=v"(b1) : "v"(p[8 * h + 6]), "v"(p[8 * h + 7]));
        uint2v s0 = __builtin_amdgcn_permlane32_swap(a0, b0, false, false);
        uint2v s1 = __builtin_amdgcn_permlane32_swap(a1, b1, false, false);
        union { unsigned u[4]; short8v v; } pa;
        pa.u[0] = s0[0]; pa.u[1] = s1[0]; pa.u[2] = s0[1]; pa.u[3] = s1[1];
        int kbase = kb + 16 * h + 8 * lh;
        short8v vf0 = *(const short8v*)(smem + 12288 +
            ((l31 * 256 + kbase * 2) ^ ((l31 & 15) << 4)));
        acc[0] = __builtin_amdgcn_mfma_f32_32x32x16_bf16(pa.v, vf0, acc[0], 0, 0, 0);
        int c1 = 32 + l31;
        short8v vf1 = *(const short8v*)(smem + 12288 +
            ((c1 * 256 + kbase * 2) ^ ((c1 & 15) << 4)));
        acc[1] = __builtin_amdgcn_mfma_f32_32x32x16_bf16(pa.v, vf1, acc[1], 0, 0, 0);
      }
    }
    __syncthreads();  // all waves done READING tile t
    // ---- T14 write-late: park prefetched tile t+1 ----
    if (hasNext) {
#pragma unroll
      for (int i = 0; i < 3; ++i) {
        *(short8v*)(smem + kloff[i]) = pfk[i];
        *(short8v*)(smem + vloff[i]) = pfv[i];
      }
    }
    __syncthreads();  // writes visible before next compute
  }

  // ---- epilogue: transpose O through LDS (per-wave [32 q][52 c]), store
  __syncthreads();
  float* ot = (float*)smem + wid * (32 * 52);
#pragma unroll
  for (int r = 0; r < 16; ++r) {
    int q = (r & 3) + 8 * (r >> 2) + 4 * lh;
    ot[q * 52 + l31] = acc[0][r];
    if (l31 < 17) ot[q * 52 + 32 + l31] = acc[1][r];
  }
  __syncthreads();
  for (int idx = lane; idx < 49 * 32; idx += 64) {
    int q = idx & 31, c = idx >> 5;
    num[((ks * 49 + c) << 14) + qbase + q] = ot[q * 52 + c];
  }
}

// ---------------- kernel 5: fused combine + divide + proj -> d_out
// 256 blocks x 256 thr; block = 64 pixels x 4 channel-groups (12 ch each).
// out = (W . sum_ks s) * (1/sum_ks den)  — division folded through linear proj.
__global__ __launch_bounds__(256) void k_combproj(const float* __restrict__ num,
                                                  const float* __restrict__ w,
                                                  float* __restrict__ out) {
  __shared__ float wl[48][48];
  __shared__ float tok[48][64];
  __shared__ float dinv[64];
  const int t = threadIdx.x;
  const int px = t & 63, grp = t >> 6;
  const int p0 = blockIdx.x * 64;
  for (int i = t; i < 48 * 48; i += 256) wl[i / 48][i % 48] = w[i];
#pragma unroll
  for (int i = 0; i < 12; ++i) {
    int c = grp * 12 + i;
    float s = 0.f;
#pragma unroll
    for (int ks = 0; ks < 8; ++ks) s += num[(ks * 49 + c) * NPIX + p0 + px];
    tok[c][px] = s;
  }
  if (grp == 0) {
    float d = 0.f;
#pragma unroll
    for (int ks = 0; ks < 8; ++ks) d += num[(ks * 49 + 48) * NPIX + p0 + px];
    dinv[px] = 1.f / d;
  }
  __syncthreads();
  float rd = dinv[px];
#pragma unroll
  for (int i = 0; i < 12; ++i) {
    int o = grp * 12 + i;
    float a = 0.f;
#pragma unroll
    for (int c = 0; c < 48; ++c) a += wl[o][c] * tok[c][px];
    out[o * NPIX + p0 + px] = a * rd;
  }
}

extern "C" void kernel_launch(void* const* d_in, const int* in_sizes, int n_in,
                              void* d_out, int out_size, void* d_ws, size_t ws_size,
                              hipStream_t stream) {
  const float* x      = (const float*)d_in[0];
  const float* qkv_w  = (const float*)d_in[1];
  const float* dw_w   = (const float*)d_in[2];
  const float* proj_w = (const float*)d_in[3];
  const float* temp   = (const float*)d_in[4];

  // workspace layout (bytes), peak 33.55 MB (proven available r9-r12):
  //   qn   bf16 [16384][48] @ 0         (dead after attn)
  //   kn   bf16 [16384][48] @ 1572864   (dead after attn)
  //   dwqb bf16 [144][16384] @ 3145728  (ch 96..143 = vb, live in attn)
  //   qkvb bf16 [144][16384] @ 7864320  (dead after dwconv)
  //   num  f32  [8][49][16384] @ 7864320 (overlays dead qkvb)
  char* wsb = (char*)d_ws;
  unsigned short* qn   = (unsigned short*)wsb;
  unsigned short* kn   = (unsigned short*)(wsb + 1572864);
  unsigned short* dwqb = (unsigned short*)(wsb + 3145728);
  unsigned short* vb   = dwqb + 96 * NPIX;
  unsigned short* qkvb = (unsigned short*)(wsb + 7864320);
  float* num  = (float*)(wsb + 7864320);

  k_qkv<<<dim3(64, 9), 256, 0, stream>>>(x, qkv_w, qkvb);
  k_dwconv<<<dim3(64, 144), 256, 0, stream>>>(qkvb, dw_w, dwqb);
  k_norm<<<dim3(256), 64, 0, stream>>>(dwqb, temp, qn, kn);
  k_attn8<<<dim3(1024), 256, 0, stream>>>(qn, kn, vb, num);
  k_combproj<<<dim3(256), 256, 0, stream>>>(num, proj_w, (float*)d_out);
}

// Round 16
// 124.668 us; speedup vs baseline: 1.1999x; 1.0784x over previous
//
#include <hip/hip_runtime.h>
#include <hip/hip_bf16.h>

#define NPIX 16384   // H*W
#define NC   48      // DIM

typedef __attribute__((ext_vector_type(16))) float f32x16;
typedef __attribute__((ext_vector_type(8))) short short8v;
typedef __attribute__((ext_vector_type(8))) unsigned short ushort8v;
typedef __attribute__((ext_vector_type(2))) unsigned int uint2v;

static __device__ __forceinline__ unsigned short f2bf(float x) {
  union { float f; unsigned u; } v; v.f = x;
  unsigned r = v.u + 0x7fffu + ((v.u >> 16) & 1u);
  return (unsigned short)(r >> 16);
}
static __device__ __forceinline__ float bf2f(unsigned short b) {
  union { unsigned u; float f; } v; v.u = ((unsigned)b) << 16;
  return v.f;
}

// ---------------- kernel 1: pointwise qkv conv -> bf16 channel-major
__global__ __launch_bounds__(256) void k_qkv(const float* __restrict__ in,
                                             const float* __restrict__ w,
                                             unsigned short* __restrict__ out) {
  int p = blockIdx.x * 256 + threadIdx.x;
  int og = blockIdx.y * 16;
  __shared__ float wl[16][NC];
  for (int i = threadIdx.x; i < 16 * NC; i += 256)
    wl[i / NC][i % NC] = w[(og + i / NC) * NC + i % NC];
  __syncthreads();
  float acc[16];
#pragma unroll
  for (int j = 0; j < 16; ++j) acc[j] = 0.f;
  for (int c = 0; c < NC; ++c) {
    float xv = in[c * NPIX + p];
#pragma unroll
    for (int j = 0; j < 16; ++j) acc[j] += xv * wl[j][c];
  }
#pragma unroll
  for (int j = 0; j < 16; ++j) out[(og + j) * NPIX + p] = f2bf(acc[j]);
}

// ---------------- kernel 2: depthwise 3x3 (bf16), LDS-tiled + vectorized.
// grid (8, 144): block = one channel x 16 rows. Stage 18x128 bf16 rows
// (zero-padded outside image) into LDS [18][136]. Each thread computes 8 px.
// Zero-pad terms add exact +-0.0 in the same (dy,dx) order -> bit-identical
// to the scalar bounds-checked version. (Audited clean; NOT in the attn
// failure family — r14's failure was the setprio in k_attn8.)
__global__ __launch_bounds__(256) void k_dwconv(const unsigned short* __restrict__ in,
                                                const float* __restrict__ w,
                                                unsigned short* __restrict__ out) {
  __shared__ unsigned short srows[18][136];
  const int o = blockIdx.y;
  const int by = blockIdx.x;   // row-tile 0..7
  const int tid = threadIdx.x;
  const float* wt = w + o * 9;
  for (int idx = tid; idx < 288; idx += 256) {
    int r = idx >> 4, cx = idx & 15;
    int gy = by * 16 + r - 1;
    ushort8v vv = {0, 0, 0, 0, 0, 0, 0, 0};
    if (gy >= 0 && gy < 128)
      vv = *(const ushort8v*)(in + o * NPIX + gy * 128 + cx * 8);
    *(ushort8v*)&srows[r][cx * 8] = vv;
  }
  __syncthreads();
  const int r = tid >> 4;            // output row within tile, 0..15
  const int x0 = (tid & 15) * 8;     // first of 8 output cols
  float row[3][10];
#pragma unroll
  for (int dy = 0; dy < 3; ++dy) {
    int lr = r + dy;
    ushort8v mid = *(const ushort8v*)&srows[lr][x0];
#pragma unroll
    for (int j = 0; j < 8; ++j) row[dy][j + 1] = bf2f(mid[j]);
    row[dy][0] = (x0 > 0) ? bf2f(srows[lr][x0 - 1]) : 0.f;
    row[dy][9] = (x0 + 8 < 128) ? bf2f(srows[lr][x0 + 8]) : 0.f;
  }
  float wv[9];
#pragma unroll
  for (int i = 0; i < 9; ++i) wv[i] = wt[i];
  unsigned short res[8];
#pragma unroll
  for (int j = 0; j < 8; ++j) {
    float acc = 0.f;
#pragma unroll
    for (int dy = 0; dy < 3; ++dy)
#pragma unroll
      for (int dx = 0; dx < 3; ++dx)
        acc += wv[dy * 3 + dx] * row[dy][j + dx];
    res[j] = f2bf(acc);
  }
  int gy = by * 16 + r;
  *(ushort8v*)(out + o * NPIX + gy * 128 + x0) = *(ushort8v*)res;
}

// ---------------- kernel 3: l2norm, q/k SPLIT across thread halves (2x TLP).
// q additionally scaled by t*log2(e) so attn softmax uses native exp2.
__global__ __launch_bounds__(256) void k_norm(const unsigned short* __restrict__ dwqb,
                                              const float* __restrict__ temp,
                                              unsigned short* __restrict__ qn,
                                              unsigned short* __restrict__ kn) {
  const int tid = threadIdx.x;
  const int p = blockIdx.x * 128 + (tid & 127);
  const int half = tid >> 7;  // 0: q, 1: k
  float t = temp[0] * 1.44269504088896f;
  const unsigned short* src = dwqb + half * 48 * NPIX;
  float v[48];
  float sq = 0.f;
#pragma unroll
  for (int c = 0; c < 48; ++c) {
    v[c] = bf2f(src[c * NPIX + p]);
    sq += v[c] * v[c];
  }
  float scale = (half == 0 ? t : 1.f) / fmaxf(sqrtf(sq), 1e-12f);
  unsigned short ob[48];
#pragma unroll
  for (int c = 0; c < 48; ++c) ob[c] = f2bf(v[c] * scale);
  unsigned short* dst = (half == 0 ? qn : kn) + p * 48;
#pragma unroll
  for (int j = 0; j < 6; ++j)
    *(ushort8v*)(dst + j * 8) = *(ushort8v*)&ob[j * 8];
}

// ---------------- kernel 4: MFMA attention NS=8 — FROZEN r11/r13-verified
// form (90.4 us, absmax 3.8e-6). DO NOT perturb scheduling in this kernel:
// launch_bounds (,N) [r8] and s_setprio [r14] both induced ~1e-4 corruption
// (codegen hazard edge around the inline-asm cvt_pk/permlane/MFMA cluster).
// Single-buffer + T14 prefetch; Vt swizzle ((c&15)<<4); grid 1024:
// ks=bidx&7 (one split per XCD), qb=bidx>>3.
__global__ __launch_bounds__(256) void k_attn8(const unsigned short* __restrict__ qn,
                                               const unsigned short* __restrict__ kn,
                                               const unsigned short* __restrict__ vb,
                                               float* __restrict__ num) {
  __shared__ __align__(16) char smem[28672];  // K 12288 B + Vt 16384 B (1 buf)
  const int tid = threadIdx.x;
  const int lane = tid & 63, wid = tid >> 6;
  const int l31 = lane & 31, lh = lane >> 5;
  const int bidx = blockIdx.x;
  const int ks = bidx & 7;
  const int qb = bidx >> 3;
  const int qbase = qb * 128 + wid * 32;

  short8v qf[3];
#pragma unroll
  for (int s = 0; s < 3; ++s)
    qf[s] = *(const short8v*)(qn + (qbase + l31) * 48 + s * 16 + lh * 8);

  f32x16 acc[2];  // [c-block]
#pragma unroll
  for (int b = 0; b < 2; ++b)
#pragma unroll
    for (int r = 0; r < 16; ++r) acc[b][r] = 0.f;

  // t-invariant staging maps
  int kgoff[3], kloff[3], vgoff[3], vloff[3];
#pragma unroll
  for (int i = 0; i < 3; ++i) {
    int chunk = tid + 256 * i;
    int key = chunk / 6, part = chunk - key * 6;
    kgoff[i] = key * 48 + part * 8;
    kloff[i] = (key * 96 + part * 16) ^ ((key & 7) << 4);
    int c2 = chunk >> 4, kp = chunk & 15;
    vgoff[i] = c2 * NPIX + kp * 8;
    vloff[i] = 12288 + ((c2 * 256 + kp * 16) ^ ((c2 & 15) << 4));
  }

  // Vt pad rows 48..63: row 48 = ones (den), rest zero. Written once.
  {
    int c = 48 + (tid >> 4), kp = tid & 15;
    unsigned short val = (c == 48) ? (unsigned short)0x3F80 : (unsigned short)0;
    ushort8v vv = {val, val, val, val, val, val, val, val};
    *(ushort8v*)(smem + 12288 + ((c * 256 + kp * 16) ^ ((c & 15) << 4))) = vv;
  }
  // prologue: stage tile 0
  {
    const int m0 = ks * 2048;
#pragma unroll
    for (int i = 0; i < 3; ++i) {
      *(short8v*)(smem + kloff[i]) = *(const short8v*)(kn + m0 * 48 + kgoff[i]);
      *(short8v*)(smem + vloff[i]) = *(const short8v*)(vb + m0 + vgoff[i]);
    }
  }
  __syncthreads();

  for (int t = 0; t < 16; ++t) {
    // ---- T14 issue-early: global loads for tile t+1 into registers ----
    short8v pfk[3], pfv[3];
    const bool hasNext = (t + 1 < 16);
    if (hasNext) {
      const int m0n = ks * 2048 + (t + 1) * 128;
#pragma unroll
      for (int i = 0; i < 3; ++i) {
        pfk[i] = *(const short8v*)(kn + m0n * 48 + kgoff[i]);
        pfv[i] = *(const short8v*)(vb + m0n + vgoff[i]);
      }
    }
    // ---- compute tile t ----
#pragma unroll
    for (int kb = 0; kb < 128; kb += 32) {
      f32x16 sacc;
#pragma unroll
      for (int r = 0; r < 16; ++r) sacc[r] = 0.f;
      int key = kb + l31;
#pragma unroll
      for (int s = 0; s < 3; ++s) {
        short8v kf = *(const short8v*)(smem +
            ((key * 96 + s * 32 + lh * 16) ^ ((key & 7) << 4)));
        sacc = __builtin_amdgcn_mfma_f32_32x32x16_bf16(kf, qf[s], sacc, 0, 0, 0);
      }
      float p[16];
#pragma unroll
      for (int r = 0; r < 16; ++r) p[r] = __builtin_amdgcn_exp2f(sacc[r]);
#pragma unroll
      for (int h = 0; h < 2; ++h) {
        unsigned a0, a1, b0, b1;
        asm("v_cvt_pk_bf16_f32 %0, %1, %2" : "=v"(a0) : "v"(p[8 * h + 0]), "v"(p[8 * h + 1]));
        asm("v_cvt_pk_bf16_f32 %0, %1, %2" : "=v"(a1) : "v"(p[8 * h + 2]), "v"(p[8 * h + 3]));
        asm("v_cvt_pk_bf16_f32 %0, %1, %2" : "=v"(b0) : "v"(p[8 * h + 4]), "v"(p[8 * h + 5]));
        asm("v_cvt_pk_bf16_f32 %0, %1, %2" : "=v"(b1) : "v"(p[8 * h + 6]), "v"(p[8 * h + 7]));
        uint2v s0 = __builtin_amdgcn_permlane32_swap(a0, b0, false, false);
        uint2v s1 = __builtin_amdgcn_permlane32_swap(a1, b1, false, false);
        union { unsigned u[4]; short8v v; } pa;
        pa.u[0] = s0[0]; pa.u[1] = s1[0]; pa.u[2] = s0[1]; pa.u[3] = s1[1];
        int kbase = kb + 16 * h + 8 * lh;
        short8v vf0 = *(const short8v*)(smem + 12288 +
            ((l31 * 256 + kbase * 2) ^ ((l31 & 15) << 4)));
        acc[0] = __builtin_amdgcn_mfma_f32_32x32x16_bf16(pa.v, vf0, acc[0], 0, 0, 0);
        int c1 = 32 + l31;
        short8v vf1 = *(const short8v*)(smem + 12288 +
            ((c1 * 256 + kbase * 2) ^ ((c1 & 15) << 4)));
        acc[1] = __builtin_amdgcn_mfma_f32_32x32x16_bf16(pa.v, vf1, acc[1], 0, 0, 0);
      }
    }
    __syncthreads();  // all waves done READING tile t
    // ---- T14 write-late: park prefetched tile t+1 ----
    if (hasNext) {
#pragma unroll
      for (int i = 0; i < 3; ++i) {
        *(short8v*)(smem + kloff[i]) = pfk[i];
        *(short8v*)(smem + vloff[i]) = pfv[i];
      }
    }
    __syncthreads();  // writes visible before next compute
  }

  // ---- epilogue: transpose O through LDS (per-wave [32 q][52 c]), store
  __syncthreads();
  float* ot = (float*)smem + wid * (32 * 52);
#pragma unroll
  for (int r = 0; r < 16; ++r) {
    int q = (r & 3) + 8 * (r >> 2) + 4 * lh;
    ot[q * 52 + l31] = acc[0][r];
    if (l31 < 17) ot[q * 52 + 32 + l31] = acc[1][r];
  }
  __syncthreads();
  for (int idx = lane; idx < 49 * 32; idx += 64) {
    int q = idx & 31, c = idx >> 5;
    num[((ks * 49 + c) << 14) + qbase + q] = ot[q * 52 + c];
  }
}

// ---------------- kernel 5: fused combine + divide + proj -> d_out
__global__ __launch_bounds__(256) void k_combproj(const float* __restrict__ num,
                                                  const float* __restrict__ w,
                                                  float* __restrict__ out) {
  __shared__ float wl[48][48];
  __shared__ float tok[48][64];
  __shared__ float dinv[64];
  const int t = threadIdx.x;
  const int px = t & 63, grp = t >> 6;
  const int p0 = blockIdx.x * 64;
  for (int i = t; i < 48 * 48; i += 256) wl[i / 48][i % 48] = w[i];
#pragma unroll
  for (int i = 0; i < 12; ++i) {
    int c = grp * 12 + i;
    float s = 0.f;
#pragma unroll
    for (int ks = 0; ks < 8; ++ks) s += num[(ks * 49 + c) * NPIX + p0 + px];
    tok[c][px] = s;
  }
  if (grp == 0) {
    float d = 0.f;
#pragma unroll
    for (int ks = 0; ks < 8; ++ks) d += num[(ks * 49 + 48) * NPIX + p0 + px];
    dinv[px] = 1.f / d;
  }
  __syncthreads();
  float rd = dinv[px];
#pragma unroll
  for (int i = 0; i < 12; ++i) {
    int o = grp * 12 + i;
    float a = 0.f;
#pragma unroll
    for (int c = 0; c < 48; ++c) a += wl[o][c] * tok[c][px];
    out[o * NPIX + p0 + px] = a * rd;
  }
}

extern "C" void kernel_launch(void* const* d_in, const int* in_sizes, int n_in,
                              void* d_out, int out_size, void* d_ws, size_t ws_size,
                              hipStream_t stream) {
  const float* x      = (const float*)d_in[0];
  const float* qkv_w  = (const float*)d_in[1];
  const float* dw_w   = (const float*)d_in[2];
  const float* proj_w = (const float*)d_in[3];
  const float* temp   = (const float*)d_in[4];

  // workspace layout (bytes), peak 33.55 MB (proven available r9-r14):
  //   qn   bf16 [16384][48] @ 0         (dead after attn)
  //   kn   bf16 [16384][48] @ 1572864   (dead after attn)
  //   dwqb bf16 [144][16384] @ 3145728  (ch 96..143 = vb, live in attn)
  //   qkvb bf16 [144][16384] @ 7864320  (dead after dwconv)
  //   num  f32  [8][49][16384] @ 7864320 (overlays dead qkvb)
  char* wsb = (char*)d_ws;
  unsigned short* qn   = (unsigned short*)wsb;
  unsigned short* kn   = (unsigned short*)(wsb + 1572864);
  unsigned short* dwqb = (unsigned short*)(wsb + 3145728);
  unsigned short* vb   = dwqb + 96 * NPIX;
  unsigned short* qkvb = (unsigned short*)(wsb + 7864320);
  float* num  = (float*)(wsb + 7864320);

  k_qkv<<<dim3(64, 9), 256, 0, stream>>>(x, qkv_w, qkvb);
  k_dwconv<<<dim3(8, 144), 256, 0, stream>>>(qkvb, dw_w, dwqb);
  k_norm<<<dim3(128), 256, 0, stream>>>(dwqb, temp, qn, kn);
  k_attn8<<<dim3(1024), 256, 0, stream>>>(qn, kn, vb, num);
  k_combproj<<<dim3(256), 256, 0, stream>>>(num, proj_w, (float*)d_out);
}